// Round 10
// baseline (481.041 us; speedup 1.0000x reference)
//
#include <hip/hip_runtime.h>

typedef unsigned short u16;
using bf16x8 = __attribute__((ext_vector_type(8))) short;
using f32x4  = __attribute__((ext_vector_type(4))) float;

#define SIB_SCALE_F 0.04419417382415922f   // 1/sqrt(512)

__device__ __forceinline__ u16 f2b(float f) {
  unsigned u = __builtin_bit_cast(unsigned, f);
  return (u16)((u + 0x7FFFu + ((u >> 16) & 1u)) >> 16);   // RNE
}

__device__ __forceinline__ float wred(float v) {
  #pragma unroll
  for (int m = 1; m < 64; m <<= 1) v += __shfl_xor(v, m);
  return v;
}

__device__ __forceinline__ void gload16(const void* g, void* l) {
  __builtin_amdgcn_global_load_lds(
      (const __attribute__((address_space(1))) unsigned int*)g,
      (__attribute__((address_space(3))) unsigned int*)l, 16, 0, 0);
}

// ---------------------------------------------------------------------------
// PERSISTENT 128x256 bf16 GEMM with store/compute overlap ("gemmQ").
// Block (mg, by): rows [mg*MT*128, +MT*128), cols [by*256, +256).
// One continuous K-stream of T = MT*NT steps (BK=32): step g = (gt, kt)
// computes K-tile kt of m-tile gt.  Double-buffered LDS (48 KB):
// A[2][128][32] + B[2][256][32], 4-slot XOR swizzle.
// STORE OVERLAP: previous m-tile's acc is snapshotted to pacc (64+64 VGPR)
// and its 16 float4-chunks are stored ONE PER STEP during the next m-tile's
// K-loop.  Per step issue order = [1 store][3 staging loads]; vmcnt(N) with
// N = ops-issued-this-step exploits IN-ORDER vmem retirement (m135) to
// drain exactly the previous step's ops -> stores retire continuously
// under MFMA instead of in a serialized end-of-tile burst.
// Swapped MFMA operands -> lane's 4 acc regs = 4 consecutive output cols.
// M % (128*MT*gridDim.x) == 0, K == 32*NT (NT=16 hardcoded), N arbitrary/256.
// ---------------------------------------------------------------------------
__global__ __launch_bounds__(512, 2) void gemmQ(
    const u16* __restrict__ A, const u16* __restrict__ B,
    const float* __restrict__ bias,
    float* __restrict__ C, int M, int N, int K, int MT)
{
  __shared__ u16 lds[24576];  // A: [0,8192) two 4096-u16 bufs; B: [8192,24576) two 8192-u16 bufs
  const int t = threadIdx.x, w = t >> 6, lane = t & 63;
  const int wm = w >> 2, wn = w & 3;          // 2m x 4n waves, wave-tile 64x64
  const int r16 = lane & 15, ks = lane >> 4;
  const int bn = blockIdx.y * 256;
  const int mg = blockIdx.x;
  const int NT = 16;                          // K = 512
  const int T = MT * NT;

  auto stageT = [&](int g2) {
    const int kt2 = g2 & 15;
    const int bm2 = (mg * MT + (g2 >> 4)) * 128;
    const int k0 = kt2 << 5;
    const int b = g2 & 1;
    {
      const int row = t >> 2;
      const int sl = (t & 3) ^ ((row >> 1) & 3);
      gload16(A + (size_t)(bm2 + row) * K + k0 + sl * 8,
              lds + b * 4096 + w * 512);
    }
    #pragma unroll
    for (int j = 0; j < 2; ++j) {
      const int row = j * 128 + (t >> 2);
      const int sl = (t & 3) ^ ((row >> 1) & 3);
      gload16(B + (size_t)(bn + row) * K + k0 + sl * 8,
              lds + 8192 + b * 8192 + j * 4096 + w * 512);
    }
  };

  // per-block bias fragments (cols fixed for all m-tiles)
  float4 biasv[4];
  #pragma unroll
  for (int n = 0; n < 4; ++n)
    biasv[n] = *(const float4*)(bias + bn + wn * 64 + n * 16 + ks * 4);

  f32x4 acc[4][4], pacc[4][4];
  #pragma unroll
  for (int m = 0; m < 4; ++m)
    #pragma unroll
    for (int n = 0; n < 4; ++n) {
      f32x4 z = {0.f, 0.f, 0.f, 0.f};
      acc[m][n] = z; pacc[m][n] = z;
    }
  int bmPrev = 0;

  // prologue: tiles 0,1
  stageT(0); stageT(1);
  asm volatile("s_waitcnt vmcnt(3)" ::: "memory");   // tile 0 landed
  __builtin_amdgcn_sched_barrier(0);
  __builtin_amdgcn_s_barrier();

  for (int gt = 0; gt < MT; ++gt) {
    const int hasStore = (gt > 0);
    #pragma unroll
    for (int kt = 0; kt < 16; ++kt) {
      const int g = gt * 16 + kt;
      const int b = kt & 1;
      const u16* Ab = lds + b * 4096;
      const u16* Bb = lds + 8192 + b * 8192;

      bf16x8 af[4], bf[4];
      #pragma unroll
      for (int m = 0; m < 4; ++m) {
        const int row = wm * 64 + m * 16 + r16;
        af[m] = *(const bf16x8*)(Ab + row * 32 + ((ks ^ ((row >> 1) & 3)) << 3));
      }
      #pragma unroll
      for (int n = 0; n < 4; ++n) {
        const int row = wn * 64 + n * 16 + r16;
        bf[n] = *(const bf16x8*)(Bb + row * 32 + ((ks ^ ((row >> 1) & 3)) << 3));
      }
      asm volatile("s_waitcnt lgkmcnt(0)" ::: "memory");
      __builtin_amdgcn_sched_barrier(0);
      __builtin_amdgcn_s_barrier();          // all reads of buf b done -> safe to restage

      // one pacc chunk store (m-tile gt-1), then staging loads for tile g+2
      if (hasStore) {
        constexpr int sm = 0; // placeholder to keep kt-static indexing below
        (void)sm;
        const int m = kt >> 2, n = kt & 3;   // kt is compile-time (unrolled)
        const int grow = bmPrev + wm * 64 + m * 16 + r16;
        const int gcol = bn + wn * 64 + n * 16 + ks * 4;
        float4 o;
        o.x = pacc[kt >> 2][kt & 3][0] + biasv[kt & 3].x;
        o.y = pacc[kt >> 2][kt & 3][1] + biasv[kt & 3].y;
        o.z = pacc[kt >> 2][kt & 3][2] + biasv[kt & 3].z;
        o.w = pacc[kt >> 2][kt & 3][3] + biasv[kt & 3].w;
        *(float4*)(C + (size_t)grow * N + gcol) = o;
        (void)m; (void)n;
      }
      const bool doStage = (g + 2 < T);
      if (doStage) stageT(g + 2);

      // drain previous step's ops (in-order retirement): allow only
      // this step's issue count to remain in flight
      if (doStage) {
        if (hasStore) asm volatile("s_waitcnt vmcnt(4)" ::: "memory");
        else          asm volatile("s_waitcnt vmcnt(3)" ::: "memory");
      } else {
        asm volatile("s_waitcnt vmcnt(1)" ::: "memory");
      }
      __builtin_amdgcn_sched_barrier(0);
      __builtin_amdgcn_s_barrier();          // tile g+1 visible to all waves

      __builtin_amdgcn_s_setprio(1);
      #pragma unroll
      for (int m = 0; m < 4; ++m)
        #pragma unroll
        for (int n = 0; n < 4; ++n)
          acc[m][n] = __builtin_amdgcn_mfma_f32_16x16x32_bf16(bf[n], af[m], acc[m][n], 0, 0, 0);
      __builtin_amdgcn_s_setprio(0);

      if (kt == 15) {                        // snapshot for spread stores
        bmPrev = (mg * MT + gt) * 128;
        #pragma unroll
        for (int m = 0; m < 4; ++m)
          #pragma unroll
          for (int n = 0; n < 4; ++n) {
            pacc[m][n] = acc[m][n];
            f32x4 z = {0.f, 0.f, 0.f, 0.f};
            acc[m][n] = z;
          }
      }
    }
  }

  // final m-tile's stores
  #pragma unroll
  for (int m = 0; m < 4; ++m) {
    const int grow = bmPrev + wm * 64 + m * 16 + r16;
    float* Crow = C + (size_t)grow * N;
    #pragma unroll
    for (int n = 0; n < 4; ++n) {
      const int gcol = bn + wn * 64 + n * 16 + ks * 4;
      float4 o;
      o.x = pacc[m][n][0] + biasv[n].x;
      o.y = pacc[m][n][1] + biasv[n].y;
      o.z = pacc[m][n][2] + biasv[n].z;
      o.w = pacc[m][n][3] + biasv[n].w;
      *(float4*)(Crow + gcol) = o;
    }
  }
}

// ---------------------------------------------------------------------------
// bf16 MFMA GEMM, 128x128 tile, BK=32, swapped-operand float4 epilogue.
// C = A@B^T + bscale*bias[level sel].  GATHER: A from Afp[tok[row]] (fp32).
// POOL: epilogue computes pooled = bf16((h0 + a0*S1 + a1*S2 + a2*v)*inv) -> P.
// ---------------------------------------------------------------------------
template <bool GATHER, bool POOL>
__global__ __launch_bounds__(256) void gemm_bf16_bt(
    const float* __restrict__ Afp, const int* __restrict__ tok,
    const u16* __restrict__ A, const u16* __restrict__ B,
    const float* __restrict__ bias, int blvl, float bscale,
    float* __restrict__ C, u16* __restrict__ Cb,
    const float* __restrict__ h0f, const float* __restrict__ S1f,
    const float* __restrict__ S2f, const float* __restrict__ psum,
    u16* __restrict__ P,
    int M, int N, int K)
{
  __shared__ u16 ldsA[128 * 32];
  __shared__ u16 ldsB[128 * 32];
  const int t = threadIdx.x;
  const int w = t >> 6;
  const int lane = t & 63;
  const int wr = w >> 1, wc = w & 1;

  const int nb = gridDim.x * gridDim.y;
  const int lid = blockIdx.y * gridDim.x + blockIdx.x;
  const int chunk = nb >> 3;
  const int nlid = (lid & 7) * chunk + (lid >> 3);
  const int bx = nlid % gridDim.x, by = nlid / gridDim.x;

  const int bm = bx * 128, bn = by * 128;
  const int r16 = lane & 15, ks = lane >> 4;
  const int srow = t >> 2, sslot = t & 3;

  f32x4 acc[4][4];
  #pragma unroll
  for (int m = 0; m < 4; ++m)
    #pragma unroll
    for (int n = 0; n < 4; ++n) {
      f32x4 z = {0.f, 0.f, 0.f, 0.f};
      acc[m][n] = z;
    }

  for (int k0 = 0; k0 < K; k0 += 32) {
    if (k0) __syncthreads();
    #pragma unroll
    for (int i = 0; i < 2; ++i) {
      const int row = srow + i * 64;
      const int sl = sslot ^ ((row >> 1) & 3);
      if constexpr (GATHER) {
        const float* src = Afp + (size_t)tok[bm + row] * 512 + k0 + sl * 8;
        const float4 a0 = *(const float4*)src;
        const float4 a1 = *(const float4*)(src + 4);
        bf16x8 v;
        v[0] = (short)f2b(a0.x); v[1] = (short)f2b(a0.y);
        v[2] = (short)f2b(a0.z); v[3] = (short)f2b(a0.w);
        v[4] = (short)f2b(a1.x); v[5] = (short)f2b(a1.y);
        v[6] = (short)f2b(a1.z); v[7] = (short)f2b(a1.w);
        *(bf16x8*)(ldsA + i * 2048 + w * 512 + lane * 8) = v;
      } else {
        gload16(A + (size_t)(bm + row) * K + k0 + sl * 8,
                ldsA + (i * 2048 + w * 512));
      }
      gload16(B + (size_t)(bn + row) * K + k0 + sl * 8,
              ldsB + (i * 2048 + w * 512));
    }
    __syncthreads();

    bf16x8 af[4], bfr[4];
    #pragma unroll
    for (int m = 0; m < 4; ++m) {
      const int row = wr * 64 + m * 16 + r16;
      af[m] = *(const bf16x8*)(ldsA + row * 32 + ((ks ^ ((row >> 1) & 3)) << 3));
    }
    #pragma unroll
    for (int n = 0; n < 4; ++n) {
      const int row = wc * 64 + n * 16 + r16;
      bfr[n] = *(const bf16x8*)(ldsB + row * 32 + ((ks ^ ((row >> 1) & 3)) << 3));
    }
    #pragma unroll
    for (int m = 0; m < 4; ++m)
      #pragma unroll
      for (int n = 0; n < 4; ++n)
        acc[m][n] = __builtin_amdgcn_mfma_f32_16x16x32_bf16(bfr[n], af[m], acc[m][n], 0, 0, 0);
  }

  const float* be = bias + (size_t)(bm >> 12) * blvl;

  float a0 = 0.f, a1 = 0.f, a2 = 0.f, inv = 0.f;
  if constexpr (POOL) {
    a0 = (psum[0] * (1.f / 4096.f) >= 0.5f) ? 1.f : 0.f;
    a1 = a0 * ((psum[1] * (1.f / 4096.f) >= 0.5f) ? 1.f : 0.f);
    a2 = a1 * ((psum[2] * (1.f / 4096.f) >= 0.5f) ? 1.f : 0.f);
    const float cnt = 1.f + a0 * 2.f + a1 * 4.f + a2 * 8.f;
    inv = 1.f / fmaxf(cnt, 1e-8f);
  }

  #pragma unroll
  for (int m = 0; m < 4; ++m) {
    const int grow = bm + wr * 64 + m * 16 + r16;
    #pragma unroll
    for (int n = 0; n < 4; ++n) {
      const int gcol = bn + wc * 64 + n * 16 + ks * 4;
      const float4 bv = *(const float4*)(be + gcol);
      float4 o;
      o.x = acc[m][n][0] + bv.x * bscale;
      o.y = acc[m][n][1] + bv.y * bscale;
      o.z = acc[m][n][2] + bv.z * bscale;
      o.w = acc[m][n][3] + bv.w * bscale;
      const size_t idx = (size_t)grow * N + gcol;
      if constexpr (POOL) {
        const float4 h = *(const float4*)(h0f + idx);
        const float4 s1 = *(const float4*)(S1f + idx);
        const float4 s2 = *(const float4*)(S2f + idx);
        ushort4 ob;
        ob.x = f2b((h.x + a0 * s1.x + a1 * s2.x + a2 * o.x) * inv);
        ob.y = f2b((h.y + a0 * s1.y + a1 * s2.y + a2 * o.y) * inv);
        ob.z = f2b((h.z + a0 * s1.z + a1 * s2.z + a2 * o.z) * inv);
        ob.w = f2b((h.w + a0 * s1.w + a1 * s2.w + a2 * o.w) * inv);
        *(ushort4*)(P + idx) = ob;
      } else {
        *(float4*)(C + idx) = o;
        if (Cb) {
          ushort4 ob = { f2b(o.x), f2b(o.y), f2b(o.z), f2b(o.w) };
          *(ushort4*)(Cb + idx) = ob;
        }
      }
    }
  }
}

// ---------------------------------------------------------------------------
// fused weight prep + out_w conversion, role-dispatched (grid 16676)
// ---------------------------------------------------------------------------
__global__ __launch_bounds__(256) void prep_misc(
    const float* __restrict__ cf_w, const float* __restrict__ cf_b,
    const float* __restrict__ sib, const float* __restrict__ proj_w,
    const float* __restrict__ f1w, const float* __restrict__ f1b,
    const float* __restrict__ f2w, const float* __restrict__ pde,
    const float* __restrict__ out_w,
    u16* __restrict__ wsum_b, u16* __restrict__ projw_b,
    u16* __restrict__ f1w512b, u16* __restrict__ f2wb,
    float* __restrict__ cvec, float* __restrict__ psum,
    float* __restrict__ y1bias, u16* __restrict__ outw_b)
{
  const int b = blockIdx.x, t = threadIdx.x;
  if (b >= 676) {
    const int idx = (b - 676) * 256 + t;
    const float4 v = ((const float4*)out_w)[idx];
    ushort4 o = { f2b(v.x), f2b(v.y), f2b(v.z), f2b(v.w) };
    ((ushort4*)outw_b)[idx] = o;
  } else if (b < 256) {
    const int idx = b * 256 + t;
    const float4 a = ((const float4*)cf_w)[idx];
    const float4 c = ((const float4*)(cf_w + 262144))[idx];
    ushort4 o = { f2b(a.x + c.x), f2b(a.y + c.y), f2b(a.z + c.z), f2b(a.w + c.w) };
    ((ushort4*)wsum_b)[idx] = o;
  } else if (b < 512) {
    const int idx = (b - 256) * 256 + t;
    const float4 v = ((const float4*)proj_w)[idx];
    ushort4 o = { f2b(v.x), f2b(v.y), f2b(v.z), f2b(v.w) };
    ((ushort4*)projw_b)[idx] = o;
  } else if (b < 640) {
    const int fi = (b - 512) * 256 + t;
    const int row = fi >> 7, c4 = fi & 127;
    const float4 v = *(const float4*)(f1w + (size_t)row * 640 + c4 * 4);
    ushort4 o = { f2b(v.x), f2b(v.y), f2b(v.z), f2b(v.w) };
    ((ushort4*)f1w512b)[row * 128 + c4] = o;
  } else if (b < 672) {
    const int idx = (b - 640) * 256 + t;
    const float4 v = ((const float4*)f2w)[idx];
    ushort4 o = { f2b(v.x), f2b(v.y), f2b(v.z), f2b(v.w) };
    ((ushort4*)f2wb)[idx] = o;
  } else if (b < 675) {
    const int l = b - 672, j = t;
    const float* wrow = f1w + (size_t)j * 640 + 512;
    const float* p = pde + l * 128;
    float s = f1b[j];
    #pragma unroll 4
    for (int k = 0; k < 128; ++k) s += wrow[k] * p[k];
    y1bias[l * 256 + j] = s;
  } else {
    cvec[t]       = cf_b[t]       + cf_b[512 + t] + SIB_SCALE_F * (sib[t]       + sib[512 + t]);
    cvec[256 + t] = cf_b[256 + t] + cf_b[768 + t] + SIB_SCALE_F * (sib[256 + t] + sib[768 + t]);
    if (t < 3) psum[t] = 0.f;
  }
}

// ---------------------------------------------------------------------------
// batched policy input over 3 levels: X[g] = bf16(LN(S_l/2^l + 0.01*dep_l))
// ---------------------------------------------------------------------------
__global__ __launch_bounds__(256) void mean_ln_concat_b(
    const float* __restrict__ S0, const float* __restrict__ S1,
    const float* __restrict__ S2,
    const float* __restrict__ dep,
    const float* __restrict__ g, const float* __restrict__ b,
    u16* __restrict__ X)
{
  const int wid = threadIdx.x >> 6, lane = threadIdx.x & 63;
  const int gr = blockIdx.x * 4 + wid;          // 0..12287
  const int l = gr >> 12, n = gr & 4095;
  const float* Sr = (l == 0 ? S0 : l == 1 ? S1 : S2) + (size_t)n * 512;
  const float invM = (l == 0 ? 1.f : l == 1 ? 0.5f : 0.25f);
  const float* depl = dep + 512 * l;
  const int c0 = lane * 8;
  float x[8];
  float s = 0.f, sq = 0.f;
  #pragma unroll
  for (int i = 0; i < 8; ++i) {
    const float v = Sr[c0 + i] * invM + 0.01f * depl[c0 + i];
    x[i] = v; s += v; sq += v * v;
  }
  s = wred(s); sq = wred(sq);
  const float mean = s * (1.f / 512.f);
  const float var = sq * (1.f / 512.f) - mean * mean;
  const float rs = rsqrtf(var + 1e-5f);
  ushort4 o0, o1;
  o0.x = f2b((x[0] - mean) * rs * g[c0 + 0] + b[c0 + 0]);
  o0.y = f2b((x[1] - mean) * rs * g[c0 + 1] + b[c0 + 1]);
  o0.z = f2b((x[2] - mean) * rs * g[c0 + 2] + b[c0 + 2]);
  o0.w = f2b((x[3] - mean) * rs * g[c0 + 3] + b[c0 + 3]);
  o1.x = f2b((x[4] - mean) * rs * g[c0 + 4] + b[c0 + 4]);
  o1.y = f2b((x[5] - mean) * rs * g[c0 + 5] + b[c0 + 5]);
  o1.z = f2b((x[6] - mean) * rs * g[c0 + 6] + b[c0 + 6]);
  o1.w = f2b((x[7] - mean) * rs * g[c0 + 7] + b[c0 + 7]);
  ushort4* Xr = (ushort4*)(X + (size_t)gr * 512);
  Xr[lane * 2]     = o0;
  Xr[lane * 2 + 1] = o1;
}

// LN + relu over 256 cols, fp32 in -> bf16 out
__global__ __launch_bounds__(256) void ln_relu_b256(
    const float* __restrict__ X, const float* __restrict__ g,
    const float* __restrict__ b, u16* __restrict__ O)
{
  const int wid = threadIdx.x >> 6, lane = threadIdx.x & 63;
  const int n = blockIdx.x * 4 + wid;
  const float* Xr = X + (size_t)n * 256;
  float x[4];
  float s = 0.f, sq = 0.f;
  #pragma unroll
  for (int i = 0; i < 4; ++i) {
    x[i] = Xr[lane * 4 + i]; s += x[i]; sq += x[i] * x[i];
  }
  s = wred(s); sq = wred(sq);
  const float mean = s * (1.f / 256.f);
  const float var = sq * (1.f / 256.f) - mean * mean;
  const float rs = rsqrtf(var + 1e-5f);
  ushort4 o;
  o.x = f2b(fmaxf((x[0] - mean) * rs * g[lane * 4 + 0] + b[lane * 4 + 0], 0.f));
  o.y = f2b(fmaxf((x[1] - mean) * rs * g[lane * 4 + 1] + b[lane * 4 + 1], 0.f));
  o.z = f2b(fmaxf((x[2] - mean) * rs * g[lane * 4 + 2] + b[lane * 4 + 2], 0.f));
  o.w = f2b(fmaxf((x[3] - mean) * rs * g[lane * 4 + 3] + b[lane * 4 + 3], 0.f));
  ((ushort4*)(O + (size_t)n * 256))[lane] = o;
}

// fused: LN(128) + relu + dot(pow_w) + sigmoid + clip + per-level atomicAdd
__global__ __launch_bounds__(256) void ln_policy128(
    const float* __restrict__ Y2, const float* __restrict__ g,
    const float* __restrict__ b, const float* __restrict__ pw,
    const float* __restrict__ pb, float* __restrict__ psum)
{
  __shared__ float part[4];
  const int wid = threadIdx.x >> 6, lane = threadIdx.x & 63;
  const int gr = blockIdx.x * 4 + wid;
  const float* Xr = Y2 + (size_t)gr * 128;
  float x[2];
  float s = 0.f, sq = 0.f;
  #pragma unroll
  for (int i = 0; i < 2; ++i) {
    x[i] = Xr[lane * 2 + i]; s += x[i]; sq += x[i] * x[i];
  }
  s = wred(s); sq = wred(sq);
  const float mean = s * (1.f / 128.f);
  const float var = sq * (1.f / 128.f) - mean * mean;
  const float rs = rsqrtf(var + 1e-5f);
  float z = 0.f;
  #pragma unroll
  for (int i = 0; i < 2; ++i) {
    const int c = lane * 2 + i;
    const float v = fmaxf((x[i] - mean) * rs * g[c] + b[c], 0.f);
    z += v * pw[c];
  }
  z = wred(z);
  if (lane == 0) {
    const float p = 1.f / (1.f + expf(-(z + pb[0])));
    part[wid] = fminf(fmaxf(p, 1e-7f), 1.f - 1e-7f);
  }
  __syncthreads();
  if (threadIdx.x == 0)
    atomicAdd(psum + (gr >> 12), part[0] + part[1] + part[2] + part[3]);
}

// ---------------------------------------------------------------------------
extern "C" void kernel_launch(void* const* d_in, const int* in_sizes, int n_in,
                              void* d_out, int out_size, void* d_ws, size_t ws_size,
                              hipStream_t stream) {
  const int*   tok    = (const int*)  d_in[0];
  const float* emb    = (const float*)d_in[1];
  const float* proj_w = (const float*)d_in[2];
  const float* proj_b = (const float*)d_in[3];
  const float* cf_w   = (const float*)d_in[4];
  const float* cf_b   = (const float*)d_in[5];
  const float* in_g   = (const float*)d_in[6];
  const float* in_b   = (const float*)d_in[7];
  const float* pde    = (const float*)d_in[8];
  const float* f1w    = (const float*)d_in[9];
  const float* f1b    = (const float*)d_in[10];
  const float* n1g    = (const float*)d_in[11];
  const float* n1b    = (const float*)d_in[12];
  const float* f2w    = (const float*)d_in[13];
  const float* f2bias = (const float*)d_in[14];
  const float* n2g    = (const float*)d_in[15];
  const float* n2b    = (const float*)d_in[16];
  const float* pow_w  = (const float*)d_in[17];
  const float* pow_b  = (const float*)d_in[18];
  const float* sib    = (const float*)d_in[19];
  const float* dep    = (const float*)d_in[20];
  const float* out_w  = (const float*)d_in[21];
  const float* out_b  = (const float*)d_in[22];
  float* out = (float*)d_out;

  char* ws = (char*)d_ws;
  size_t off = 0;
  auto alloc = [&](size_t bytes) -> void* {
    void* p = ws + off;
    off += (bytes + 255) & ~(size_t)255;
    return p;
  };
  u16*   outw_b  = (u16*)  alloc((size_t)32000 * 512 * 2);
  u16*   projw_b = (u16*)  alloc((size_t)512 * 512 * 2);
  u16*   wsum_b  = (u16*)  alloc((size_t)512 * 512 * 2);
  u16*   f1w512b = (u16*)  alloc((size_t)256 * 512 * 2);
  u16*   f2wb    = (u16*)  alloc((size_t)128 * 256 * 2);
  float* h0f     = (float*)alloc((size_t)4096 * 512 * 4);
  u16*   h0b     = (u16*)  alloc((size_t)4096 * 512 * 2);
  float* S1f     = (float*)alloc((size_t)4096 * 512 * 4);
  u16*   S1b     = (u16*)  alloc((size_t)4096 * 512 * 2);
  float* S2f     = (float*)alloc((size_t)4096 * 512 * 4);
  u16*   S2b     = (u16*)  alloc((size_t)4096 * 512 * 2);
  u16*   X       = (u16*)  alloc((size_t)12288 * 512 * 2);
  float* Y1      = (float*)alloc((size_t)12288 * 256 * 4);
  u16*   Y1b     = (u16*)  alloc((size_t)12288 * 256 * 2);
  float* Y2      = (float*)alloc((size_t)12288 * 128 * 4);
  float* y1bias  = (float*)alloc(3 * 256 * 4);
  float* cvec    = (float*)alloc(512 * 4);
  float* psum    = (float*)alloc(256);
  u16*   poolb   = (u16*)  alloc((size_t)4096 * 512 * 2);

  prep_misc<<<16676, 256, 0, stream>>>(cf_w, cf_b, sib, proj_w, f1w, f1b, f2w,
                                       pde, out_w,
                                       wsum_b, projw_b, f1w512b, f2wb,
                                       cvec, psum, y1bias, outw_b);

  // h0 = emb[tok] @ proj_w^T + proj_b
  gemm_bf16_bt<true, false><<<dim3(32, 4), 256, 0, stream>>>(
      emb, tok, nullptr, projw_b, proj_b, 0, 1.f, h0f, h0b,
      nullptr, nullptr, nullptr, nullptr, nullptr, 4096, 512, 512);
  // S1, S2
  gemm_bf16_bt<false, false><<<dim3(32, 4), 256, 0, stream>>>(
      nullptr, nullptr, h0b, wsum_b, cvec, 0, 1.f, S1f, S1b,
      nullptr, nullptr, nullptr, nullptr, nullptr, 4096, 512, 512);
  gemm_bf16_bt<false, false><<<dim3(32, 4), 256, 0, stream>>>(
      nullptr, nullptr, S1b, wsum_b, cvec, 0, 2.f, S2f, S2b,
      nullptr, nullptr, nullptr, nullptr, nullptr, 4096, 512, 512);

  // policy, 3 levels batched
  mean_ln_concat_b<<<3072, 256, 0, stream>>>(h0f, S1f, S2f, dep, in_g, in_b, X);
  gemm_bf16_bt<false, false><<<dim3(96, 2), 256, 0, stream>>>(
      nullptr, nullptr, X, f1w512b, y1bias, 256, 1.f, Y1, nullptr,
      nullptr, nullptr, nullptr, nullptr, nullptr, 12288, 256, 512);
  ln_relu_b256<<<3072, 256, 0, stream>>>(Y1, n1g, n1b, Y1b);
  gemm_bf16_bt<false, false><<<dim3(96, 1), 256, 0, stream>>>(
      nullptr, nullptr, Y1b, f2wb, f2bias, 0, 1.f, Y2, nullptr,
      nullptr, nullptr, nullptr, nullptr, nullptr, 12288, 128, 256);
  ln_policy128<<<3072, 256, 0, stream>>>(Y2, n2g, n2b, pow_w, pow_b, psum);

  // S3 GEMM fused with pooling
  gemm_bf16_bt<false, true><<<dim3(32, 4), 256, 0, stream>>>(
      nullptr, nullptr, S2b, wsum_b, cvec, 0, 4.f, nullptr, nullptr,
      h0f, S1f, S2f, psum, poolb, 4096, 512, 512);

  // out = pooled @ out_w^T + out_b (4096 x 32000 x 512)
  // persistent 128x256, spread stores: grid (2, 125), MT=16
  gemmQ<<<dim3(2, 125), 512, 0, stream>>>(poolb, outw_b, out_b,
                                          out, 4096, 32000, 512, 16);
}

// Round 11
// 395.332 us; speedup vs baseline: 1.2168x; 1.2168x over previous
//
#include <hip/hip_runtime.h>

typedef unsigned short u16;
using bf16x8 = __attribute__((ext_vector_type(8))) short;
using f32x4  = __attribute__((ext_vector_type(4))) float;

#define SIB_SCALE_F 0.04419417382415922f   // 1/sqrt(512)

__device__ __forceinline__ u16 f2b(float f) {
  unsigned u = __builtin_bit_cast(unsigned, f);
  return (u16)((u + 0x7FFFu + ((u >> 16) & 1u)) >> 16);   // RNE
}

__device__ __forceinline__ float wred(float v) {
  #pragma unroll
  for (int m = 1; m < 64; m <<= 1) v += __shfl_xor(v, m);
  return v;
}

__device__ __forceinline__ void gload16(const void* g, void* l) {
  __builtin_amdgcn_global_load_lds(
      (const __attribute__((address_space(1))) unsigned int*)g,
      (__attribute__((address_space(3))) unsigned int*)l, 16, 0, 0);
}

// ---------------------------------------------------------------------------
// PERSISTENT 256x256 bf16 MFMA GEMM, 8-phase pipeline (R8/R9-proven).
// Swapped MFMA operands -> float4 epilogue stores.
// NEW (R11): per-block m-tile order staggered by (by & 7) so the 250 blocks'
// 262KB epilogue bursts de-synchronize -> L2 absorbs them instead of 8MB
// synchronized dirty bursts backpressuring to HBM at every m-tile seam.
// Coverage stays bijective; B-panel reuse (fixed by) unaffected.
// ---------------------------------------------------------------------------
__global__ __launch_bounds__(512, 2) void gemmP(
    const u16* __restrict__ A, const u16* __restrict__ B,
    const float* __restrict__ bias,
    float* __restrict__ C, int M, int N, int K, int MT)
{
  __shared__ u16 lds[65536];   // A: [0,32768) ; B: [32768,65536)  (u16 units)
  const int t = threadIdx.x, w = t >> 6, lane = t & 63;
  const int wm = w >> 2, wn = w & 3;
  const int r16 = lane & 15, ks = lane >> 4;

  const int bn = blockIdx.y * 256;
  const int mg = blockIdx.x;
  const int NT = K >> 6;
  const int stag = blockIdx.y & (MT - 1);     // burst de-synchronization

  auto stageH = [&](const u16* __restrict__ G, int grow0, int kt, int half, int opBase) {
    const int k0 = kt << 6;
    u16* dst = lds + opBase + ((kt & 1) << 14) + (half << 13);
    #pragma unroll
    for (int j = 0; j < 2; ++j) {
      const int r = half * 128 + j * 64 + w * 8 + (lane >> 3);
      const int s = (lane & 7) ^ (r & 7);
      gload16(G + (size_t)(grow0 + r) * K + k0 + s * 8,
              dst + j * 4096 + w * 512);
    }
  };

  for (int mt0 = 0; mt0 < MT; ++mt0) {
    const int mt = (mt0 + stag) & (MT - 1);
    const int bm = (mg * MT + mt) * 256;

    f32x4 acc[8][4];
    #pragma unroll
    for (int m = 0; m < 8; ++m)
      #pragma unroll
      for (int n = 0; n < 4; ++n) {
        f32x4 z = {0.f, 0.f, 0.f, 0.f};
        acc[m][n] = z;
      }

    __builtin_amdgcn_sched_barrier(0);
    stageH(A, bm, 0, 0, 0);
    stageH(A, bm, 0, 1, 0);
    stageH(B, bn, 0, 0, 32768);
    stageH(B, bn, 0, 1, 32768);
    __builtin_amdgcn_sched_barrier(0);
    stageH(B, bn, 1, 0, 32768);
    stageH(B, bn, 1, 1, 32768);
    asm volatile("s_waitcnt vmcnt(4)" ::: "memory");
    __builtin_amdgcn_sched_barrier(0);
    __builtin_amdgcn_s_barrier();

    for (int kt = 0; kt < NT; ++kt) {
      const u16* Ab = lds + ((kt & 1) << 14);
      const u16* Bb = lds + 32768 + ((kt & 1) << 14);
      bf16x8 bfr[4][2];

      #pragma unroll
      for (int p = 0; p < 4; ++p) {
        bf16x8 af2[2][2];
        #pragma unroll
        for (int i = 0; i < 2; ++i) {
          const int row = wm * 128 + (2 * p + i) * 16 + r16;
          af2[i][0] = *(const bf16x8*)(Ab + row * 64 + ((ks ^ (row & 7)) << 3));
          af2[i][1] = *(const bf16x8*)(Ab + row * 64 + (((4 + ks) ^ (row & 7)) << 3));
        }
        if (p == 0) {
          #pragma unroll
          for (int n = 0; n < 4; ++n) {
            const int row = wn * 64 + n * 16 + r16;
            bfr[n][0] = *(const bf16x8*)(Bb + row * 64 + ((ks ^ (row & 7)) << 3));
            bfr[n][1] = *(const bf16x8*)(Bb + row * 64 + (((4 + ks) ^ (row & 7)) << 3));
          }
        }
        if (p == 0 && kt + 1 < NT) stageH(A, bm, kt + 1, 0, 0);
        if (p == 1 && kt + 1 < NT) stageH(A, bm, kt + 1, 1, 0);
        if (p == 2 && kt + 2 < NT) stageH(B, bn, kt + 2, 0, 32768);
        if (p == 3) {
          if (kt + 2 < NT) {
            stageH(B, bn, kt + 2, 1, 32768);
            asm volatile("s_waitcnt vmcnt(4)" ::: "memory");
          } else {
            asm volatile("s_waitcnt vmcnt(0)" ::: "memory");
          }
          __builtin_amdgcn_sched_barrier(0);
        }
        __builtin_amdgcn_s_barrier();
        asm volatile("s_waitcnt lgkmcnt(0)" ::: "memory");
        __builtin_amdgcn_sched_barrier(0);
        __builtin_amdgcn_s_setprio(1);
        #pragma unroll
        for (int i = 0; i < 2; ++i)
          #pragma unroll
          for (int n = 0; n < 4; ++n) {
            acc[2 * p + i][n] = __builtin_amdgcn_mfma_f32_16x16x32_bf16(
                bfr[n][0], af2[i][0], acc[2 * p + i][n], 0, 0, 0);
            acc[2 * p + i][n] = __builtin_amdgcn_mfma_f32_16x16x32_bf16(
                bfr[n][1], af2[i][1], acc[2 * p + i][n], 0, 0, 0);
          }
        __builtin_amdgcn_s_setprio(0);
        __builtin_amdgcn_s_barrier();
      }
    }

    #pragma unroll
    for (int m = 0; m < 8; ++m) {
      const int grow = bm + wm * 128 + m * 16 + r16;
      float* Crow = C + (size_t)grow * N;
      #pragma unroll
      for (int n = 0; n < 4; ++n) {
        const int gcol = bn + wn * 64 + n * 16 + ks * 4;
        const float4 bv = *(const float4*)(bias + gcol);
        float4 o;
        o.x = acc[m][n][0] + bv.x;
        o.y = acc[m][n][1] + bv.y;
        o.z = acc[m][n][2] + bv.z;
        o.w = acc[m][n][3] + bv.w;
        *(float4*)(Crow + gcol) = o;
      }
    }
  }
}

// ---------------------------------------------------------------------------
// bf16 MFMA GEMM, 128x128 tile, BK=32, swapped-operand float4 epilogue.
// C = A@B^T + bscale*bias[level sel].  GATHER: A from Afp[tok[row]] (fp32).
// POOL: epilogue computes pooled = bf16((h0 + a0*S1 + a1*S2 + a2*v)*inv) -> P.
// ---------------------------------------------------------------------------
template <bool GATHER, bool POOL>
__global__ __launch_bounds__(256) void gemm_bf16_bt(
    const float* __restrict__ Afp, const int* __restrict__ tok,
    const u16* __restrict__ A, const u16* __restrict__ B,
    const float* __restrict__ bias, int blvl, float bscale,
    float* __restrict__ C, u16* __restrict__ Cb,
    const float* __restrict__ h0f, const float* __restrict__ S1f,
    const float* __restrict__ S2f, const float* __restrict__ psum,
    u16* __restrict__ P,
    int M, int N, int K)
{
  __shared__ u16 ldsA[128 * 32];
  __shared__ u16 ldsB[128 * 32];
  const int t = threadIdx.x;
  const int w = t >> 6;
  const int lane = t & 63;
  const int wr = w >> 1, wc = w & 1;

  const int nb = gridDim.x * gridDim.y;
  const int lid = blockIdx.y * gridDim.x + blockIdx.x;
  const int chunk = nb >> 3;
  const int nlid = (lid & 7) * chunk + (lid >> 3);
  const int bx = nlid % gridDim.x, by = nlid / gridDim.x;

  const int bm = bx * 128, bn = by * 128;
  const int r16 = lane & 15, ks = lane >> 4;
  const int srow = t >> 2, sslot = t & 3;

  f32x4 acc[4][4];
  #pragma unroll
  for (int m = 0; m < 4; ++m)
    #pragma unroll
    for (int n = 0; n < 4; ++n) {
      f32x4 z = {0.f, 0.f, 0.f, 0.f};
      acc[m][n] = z;
    }

  for (int k0 = 0; k0 < K; k0 += 32) {
    if (k0) __syncthreads();
    #pragma unroll
    for (int i = 0; i < 2; ++i) {
      const int row = srow + i * 64;
      const int sl = sslot ^ ((row >> 1) & 3);
      if constexpr (GATHER) {
        const float* src = Afp + (size_t)tok[bm + row] * 512 + k0 + sl * 8;
        const float4 a0 = *(const float4*)src;
        const float4 a1 = *(const float4*)(src + 4);
        bf16x8 v;
        v[0] = (short)f2b(a0.x); v[1] = (short)f2b(a0.y);
        v[2] = (short)f2b(a0.z); v[3] = (short)f2b(a0.w);
        v[4] = (short)f2b(a1.x); v[5] = (short)f2b(a1.y);
        v[6] = (short)f2b(a1.z); v[7] = (short)f2b(a1.w);
        *(bf16x8*)(ldsA + i * 2048 + w * 512 + lane * 8) = v;
      } else {
        gload16(A + (size_t)(bm + row) * K + k0 + sl * 8,
                ldsA + (i * 2048 + w * 512));
      }
      gload16(B + (size_t)(bn + row) * K + k0 + sl * 8,
              ldsB + (i * 2048 + w * 512));
    }
    __syncthreads();

    bf16x8 af[4], bfr[4];
    #pragma unroll
    for (int m = 0; m < 4; ++m) {
      const int row = wr * 64 + m * 16 + r16;
      af[m] = *(const bf16x8*)(ldsA + row * 32 + ((ks ^ ((row >> 1) & 3)) << 3));
    }
    #pragma unroll
    for (int n = 0; n < 4; ++n) {
      const int row = wc * 64 + n * 16 + r16;
      bfr[n] = *(const bf16x8*)(ldsB + row * 32 + ((ks ^ ((row >> 1) & 3)) << 3));
    }
    #pragma unroll
    for (int m = 0; m < 4; ++m)
      #pragma unroll
      for (int n = 0; n < 4; ++n)
        acc[m][n] = __builtin_amdgcn_mfma_f32_16x16x32_bf16(bfr[n], af[m], acc[m][n], 0, 0, 0);
  }

  const float* be = bias + (size_t)(bm >> 12) * blvl;

  float a0 = 0.f, a1 = 0.f, a2 = 0.f, inv = 0.f;
  if constexpr (POOL) {
    a0 = (psum[0] * (1.f / 4096.f) >= 0.5f) ? 1.f : 0.f;
    a1 = a0 * ((psum[1] * (1.f / 4096.f) >= 0.5f) ? 1.f : 0.f);
    a2 = a1 * ((psum[2] * (1.f / 4096.f) >= 0.5f) ? 1.f : 0.f);
    const float cnt = 1.f + a0 * 2.f + a1 * 4.f + a2 * 8.f;
    inv = 1.f / fmaxf(cnt, 1e-8f);
  }

  #pragma unroll
  for (int m = 0; m < 4; ++m) {
    const int grow = bm + wr * 64 + m * 16 + r16;
    #pragma unroll
    for (int n = 0; n < 4; ++n) {
      const int gcol = bn + wc * 64 + n * 16 + ks * 4;
      const float4 bv = *(const float4*)(be + gcol);
      float4 o;
      o.x = acc[m][n][0] + bv.x * bscale;
      o.y = acc[m][n][1] + bv.y * bscale;
      o.z = acc[m][n][2] + bv.z * bscale;
      o.w = acc[m][n][3] + bv.w * bscale;
      const size_t idx = (size_t)grow * N + gcol;
      if constexpr (POOL) {
        const float4 h = *(const float4*)(h0f + idx);
        const float4 s1 = *(const float4*)(S1f + idx);
        const float4 s2 = *(const float4*)(S2f + idx);
        ushort4 ob;
        ob.x = f2b((h.x + a0 * s1.x + a1 * s2.x + a2 * o.x) * inv);
        ob.y = f2b((h.y + a0 * s1.y + a1 * s2.y + a2 * o.y) * inv);
        ob.z = f2b((h.z + a0 * s1.z + a1 * s2.z + a2 * o.z) * inv);
        ob.w = f2b((h.w + a0 * s1.w + a1 * s2.w + a2 * o.w) * inv);
        *(ushort4*)(P + idx) = ob;
      } else {
        *(float4*)(C + idx) = o;
        if (Cb) {
          ushort4 ob = { f2b(o.x), f2b(o.y), f2b(o.z), f2b(o.w) };
          *(ushort4*)(Cb + idx) = ob;
        }
      }
    }
  }
}

// ---------------------------------------------------------------------------
// fused weight prep + out_w conversion, role-dispatched (grid 16676)
// ---------------------------------------------------------------------------
__global__ __launch_bounds__(256) void prep_misc(
    const float* __restrict__ cf_w, const float* __restrict__ cf_b,
    const float* __restrict__ sib, const float* __restrict__ proj_w,
    const float* __restrict__ f1w, const float* __restrict__ f1b,
    const float* __restrict__ f2w, const float* __restrict__ pde,
    const float* __restrict__ out_w,
    u16* __restrict__ wsum_b, u16* __restrict__ projw_b,
    u16* __restrict__ f1w512b, u16* __restrict__ f2wb,
    float* __restrict__ cvec, float* __restrict__ psum,
    float* __restrict__ y1bias, u16* __restrict__ outw_b)
{
  const int b = blockIdx.x, t = threadIdx.x;
  if (b >= 676) {
    const int idx = (b - 676) * 256 + t;
    const float4 v = ((const float4*)out_w)[idx];
    ushort4 o = { f2b(v.x), f2b(v.y), f2b(v.z), f2b(v.w) };
    ((ushort4*)outw_b)[idx] = o;
  } else if (b < 256) {
    const int idx = b * 256 + t;
    const float4 a = ((const float4*)cf_w)[idx];
    const float4 c = ((const float4*)(cf_w + 262144))[idx];
    ushort4 o = { f2b(a.x + c.x), f2b(a.y + c.y), f2b(a.z + c.z), f2b(a.w + c.w) };
    ((ushort4*)wsum_b)[idx] = o;
  } else if (b < 512) {
    const int idx = (b - 256) * 256 + t;
    const float4 v = ((const float4*)proj_w)[idx];
    ushort4 o = { f2b(v.x), f2b(v.y), f2b(v.z), f2b(v.w) };
    ((ushort4*)projw_b)[idx] = o;
  } else if (b < 640) {
    const int fi = (b - 512) * 256 + t;
    const int row = fi >> 7, c4 = fi & 127;
    const float4 v = *(const float4*)(f1w + (size_t)row * 640 + c4 * 4);
    ushort4 o = { f2b(v.x), f2b(v.y), f2b(v.z), f2b(v.w) };
    ((ushort4*)f1w512b)[row * 128 + c4] = o;
  } else if (b < 672) {
    const int idx = (b - 640) * 256 + t;
    const float4 v = ((const float4*)f2w)[idx];
    ushort4 o = { f2b(v.x), f2b(v.y), f2b(v.z), f2b(v.w) };
    ((ushort4*)f2wb)[idx] = o;
  } else if (b < 675) {
    const int l = b - 672, j = t;
    const float* wrow = f1w + (size_t)j * 640 + 512;
    const float* p = pde + l * 128;
    float s = f1b[j];
    #pragma unroll 4
    for (int k = 0; k < 128; ++k) s += wrow[k] * p[k];
    y1bias[l * 256 + j] = s;
  } else {
    cvec[t]       = cf_b[t]       + cf_b[512 + t] + SIB_SCALE_F * (sib[t]       + sib[512 + t]);
    cvec[256 + t] = cf_b[256 + t] + cf_b[768 + t] + SIB_SCALE_F * (sib[256 + t] + sib[768 + t]);
    if (t < 3) psum[t] = 0.f;
  }
}

// ---------------------------------------------------------------------------
// batched policy input over 3 levels: X[g] = bf16(LN(S_l/2^l + 0.01*dep_l))
// ---------------------------------------------------------------------------
__global__ __launch_bounds__(256) void mean_ln_concat_b(
    const float* __restrict__ S0, const float* __restrict__ S1,
    const float* __restrict__ S2,
    const float* __restrict__ dep,
    const float* __restrict__ g, const float* __restrict__ b,
    u16* __restrict__ X)
{
  const int wid = threadIdx.x >> 6, lane = threadIdx.x & 63;
  const int gr = blockIdx.x * 4 + wid;          // 0..12287
  const int l = gr >> 12, n = gr & 4095;
  const float* Sr = (l == 0 ? S0 : l == 1 ? S1 : S2) + (size_t)n * 512;
  const float invM = (l == 0 ? 1.f : l == 1 ? 0.5f : 0.25f);
  const float* depl = dep + 512 * l;
  const int c0 = lane * 8;
  float x[8];
  float s = 0.f, sq = 0.f;
  #pragma unroll
  for (int i = 0; i < 8; ++i) {
    const float v = Sr[c0 + i] * invM + 0.01f * depl[c0 + i];
    x[i] = v; s += v; sq += v * v;
  }
  s = wred(s); sq = wred(sq);
  const float mean = s * (1.f / 512.f);
  const float var = sq * (1.f / 512.f) - mean * mean;
  const float rs = rsqrtf(var + 1e-5f);
  ushort4 o0, o1;
  o0.x = f2b((x[0] - mean) * rs * g[c0 + 0] + b[c0 + 0]);
  o0.y = f2b((x[1] - mean) * rs * g[c0 + 1] + b[c0 + 1]);
  o0.z = f2b((x[2] - mean) * rs * g[c0 + 2] + b[c0 + 2]);
  o0.w = f2b((x[3] - mean) * rs * g[c0 + 3] + b[c0 + 3]);
  o1.x = f2b((x[4] - mean) * rs * g[c0 + 4] + b[c0 + 4]);
  o1.y = f2b((x[5] - mean) * rs * g[c0 + 5] + b[c0 + 5]);
  o1.z = f2b((x[6] - mean) * rs * g[c0 + 6] + b[c0 + 6]);
  o1.w = f2b((x[7] - mean) * rs * g[c0 + 7] + b[c0 + 7]);
  ushort4* Xr = (ushort4*)(X + (size_t)gr * 512);
  Xr[lane * 2]     = o0;
  Xr[lane * 2 + 1] = o1;
}

// LN + relu over 256 cols, fp32 in -> bf16 out
__global__ __launch_bounds__(256) void ln_relu_b256(
    const float* __restrict__ X, const float* __restrict__ g,
    const float* __restrict__ b, u16* __restrict__ O)
{
  const int wid = threadIdx.x >> 6, lane = threadIdx.x & 63;
  const int n = blockIdx.x * 4 + wid;
  const float* Xr = X + (size_t)n * 256;
  float x[4];
  float s = 0.f, sq = 0.f;
  #pragma unroll
  for (int i = 0; i < 4; ++i) {
    x[i] = Xr[lane * 4 + i]; s += x[i]; sq += x[i] * x[i];
  }
  s = wred(s); sq = wred(sq);
  const float mean = s * (1.f / 256.f);
  const float var = sq * (1.f / 256.f) - mean * mean;
  const float rs = rsqrtf(var + 1e-5f);
  ushort4 o;
  o.x = f2b(fmaxf((x[0] - mean) * rs * g[lane * 4 + 0] + b[lane * 4 + 0], 0.f));
  o.y = f2b(fmaxf((x[1] - mean) * rs * g[lane * 4 + 1] + b[lane * 4 + 1], 0.f));
  o.z = f2b(fmaxf((x[2] - mean) * rs * g[lane * 4 + 2] + b[lane * 4 + 2], 0.f));
  o.w = f2b(fmaxf((x[3] - mean) * rs * g[lane * 4 + 3] + b[lane * 4 + 3], 0.f));
  ((ushort4*)(O + (size_t)n * 256))[lane] = o;
}

// fused: LN(128) + relu + dot(pow_w) + sigmoid + clip + per-level atomicAdd
__global__ __launch_bounds__(256) void ln_policy128(
    const float* __restrict__ Y2, const float* __restrict__ g,
    const float* __restrict__ b, const float* __restrict__ pw,
    const float* __restrict__ pb, float* __restrict__ psum)
{
  __shared__ float part[4];
  const int wid = threadIdx.x >> 6, lane = threadIdx.x & 63;
  const int gr = blockIdx.x * 4 + wid;
  const float* Xr = Y2 + (size_t)gr * 128;
  float x[2];
  float s = 0.f, sq = 0.f;
  #pragma unroll
  for (int i = 0; i < 2; ++i) {
    x[i] = Xr[lane * 2 + i]; s += x[i]; sq += x[i] * x[i];
  }
  s = wred(s); sq = wred(sq);
  const float mean = s * (1.f / 128.f);
  const float var = sq * (1.f / 128.f) - mean * mean;
  const float rs = rsqrtf(var + 1e-5f);
  float z = 0.f;
  #pragma unroll
  for (int i = 0; i < 2; ++i) {
    const int c = lane * 2 + i;
    const float v = fmaxf((x[i] - mean) * rs * g[c] + b[c], 0.f);
    z += v * pw[c];
  }
  z = wred(z);
  if (lane == 0) {
    const float p = 1.f / (1.f + expf(-(z + pb[0])));
    part[wid] = fminf(fmaxf(p, 1e-7f), 1.f - 1e-7f);
  }
  __syncthreads();
  if (threadIdx.x == 0)
    atomicAdd(psum + (gr >> 12), part[0] + part[1] + part[2] + part[3]);
}

// ---------------------------------------------------------------------------
extern "C" void kernel_launch(void* const* d_in, const int* in_sizes, int n_in,
                              void* d_out, int out_size, void* d_ws, size_t ws_size,
                              hipStream_t stream) {
  const int*   tok    = (const int*)  d_in[0];
  const float* emb    = (const float*)d_in[1];
  const float* proj_w = (const float*)d_in[2];
  const float* proj_b = (const float*)d_in[3];
  const float* cf_w   = (const float*)d_in[4];
  const float* cf_b   = (const float*)d_in[5];
  const float* in_g   = (const float*)d_in[6];
  const float* in_b   = (const float*)d_in[7];
  const float* pde    = (const float*)d_in[8];
  const float* f1w    = (const float*)d_in[9];
  const float* f1b    = (const float*)d_in[10];
  const float* n1g    = (const float*)d_in[11];
  const float* n1b    = (const float*)d_in[12];
  const float* f2w    = (const float*)d_in[13];
  const float* f2bias = (const float*)d_in[14];
  const float* n2g    = (const float*)d_in[15];
  const float* n2b    = (const float*)d_in[16];
  const float* pow_w  = (const float*)d_in[17];
  const float* pow_b  = (const float*)d_in[18];
  const float* sib    = (const float*)d_in[19];
  const float* dep    = (const float*)d_in[20];
  const float* out_w  = (const float*)d_in[21];
  const float* out_b  = (const float*)d_in[22];
  float* out = (float*)d_out;

  char* ws = (char*)d_ws;
  size_t off = 0;
  auto alloc = [&](size_t bytes) -> void* {
    void* p = ws + off;
    off += (bytes + 255) & ~(size_t)255;
    return p;
  };
  u16*   outw_b  = (u16*)  alloc((size_t)32000 * 512 * 2);
  u16*   projw_b = (u16*)  alloc((size_t)512 * 512 * 2);
  u16*   wsum_b  = (u16*)  alloc((size_t)512 * 512 * 2);
  u16*   f1w512b = (u16*)  alloc((size_t)256 * 512 * 2);
  u16*   f2wb    = (u16*)  alloc((size_t)128 * 256 * 2);
  float* h0f     = (float*)alloc((size_t)4096 * 512 * 4);
  u16*   h0b     = (u16*)  alloc((size_t)4096 * 512 * 2);
  float* S1f     = (float*)alloc((size_t)4096 * 512 * 4);
  u16*   S1b     = (u16*)  alloc((size_t)4096 * 512 * 2);
  float* S2f     = (float*)alloc((size_t)4096 * 512 * 4);
  u16*   S2b     = (u16*)  alloc((size_t)4096 * 512 * 2);
  u16*   X       = (u16*)  alloc((size_t)12288 * 512 * 2);
  float* Y1      = (float*)alloc((size_t)12288 * 256 * 4);
  u16*   Y1b     = (u16*)  alloc((size_t)12288 * 256 * 2);
  float* Y2      = (float*)alloc((size_t)12288 * 128 * 4);
  float* y1bias  = (float*)alloc(3 * 256 * 4);
  float* cvec    = (float*)alloc(512 * 4);
  float* psum    = (float*)alloc(256);
  u16*   poolb   = (u16*)  alloc((size_t)4096 * 512 * 2);

  prep_misc<<<16676, 256, 0, stream>>>(cf_w, cf_b, sib, proj_w, f1w, f1b, f2w,
                                       pde, out_w,
                                       wsum_b, projw_b, f1w512b, f2wb,
                                       cvec, psum, y1bias, outw_b);

  // h0 = emb[tok] @ proj_w^T + proj_b
  gemm_bf16_bt<true, false><<<dim3(32, 4), 256, 0, stream>>>(
      emb, tok, nullptr, projw_b, proj_b, 0, 1.f, h0f, h0b,
      nullptr, nullptr, nullptr, nullptr, nullptr, 4096, 512, 512);
  // S1, S2
  gemm_bf16_bt<false, false><<<dim3(32, 4), 256, 0, stream>>>(
      nullptr, nullptr, h0b, wsum_b, cvec, 0, 1.f, S1f, S1b,
      nullptr, nullptr, nullptr, nullptr, nullptr, 4096, 512, 512);
  gemm_bf16_bt<false, false><<<dim3(32, 4), 256, 0, stream>>>(
      nullptr, nullptr, S1b, wsum_b, cvec, 0, 2.f, S2f, S2b,
      nullptr, nullptr, nullptr, nullptr, nullptr, 4096, 512, 512);

  // policy, 3 levels batched
  mean_ln_concat_b<<<3072, 256, 0, stream>>>(h0f, S1f, S2f, dep, in_g, in_b, X);
  gemm_bf16_bt<false, false><<<dim3(96, 2), 256, 0, stream>>>(
      nullptr, nullptr, X, f1w512b, y1bias, 256, 1.f, Y1, nullptr,
      nullptr, nullptr, nullptr, nullptr, nullptr, 12288, 256, 512);
  ln_relu_b256<<<3072, 256, 0, stream>>>(Y1, n1g, n1b, Y1b);
  gemm_bf16_bt<false, false><<<dim3(96, 1), 256, 0, stream>>>(
      nullptr, nullptr, Y1b, f2wb, f2bias, 0, 1.f, Y2, nullptr,
      nullptr, nullptr, nullptr, nullptr, nullptr, 12288, 128, 256);
  ln_policy128<<<3072, 256, 0, stream>>>(Y2, n2g, n2b, pow_w, pow_b, psum);

  // S3 GEMM fused with pooling
  gemm_bf16_bt<false, true><<<dim3(32, 4), 256, 0, stream>>>(
      nullptr, nullptr, S2b, wsum_b, cvec, 0, 4.f, nullptr, nullptr,
      h0f, S1f, S2f, psum, poolb, 4096, 512, 512);

  // out = pooled @ out_w^T + out_b (4096 x 32000 x 512)
  // persistent 256x256 8-phase, m-tile order staggered per block
  gemmP<<<dim3(2, 125), 512, 0, stream>>>(poolb, outw_b, out_b,
                                          out, 4096, 32000, 512, 8);
}

// Round 13
// 378.779 us; speedup vs baseline: 1.2700x; 1.0437x over previous
//
#include <hip/hip_runtime.h>

typedef unsigned short u16;
using bf16x8 = __attribute__((ext_vector_type(8))) short;
using f32x4  = __attribute__((ext_vector_type(4))) float;

#define SIB_SCALE_F 0.04419417382415922f   // 1/sqrt(512)

__device__ __forceinline__ u16 f2b(float f) {
  unsigned u = __builtin_bit_cast(unsigned, f);
  return (u16)((u + 0x7FFFu + ((u >> 16) & 1u)) >> 16);   // RNE
}

__device__ __forceinline__ float wred(float v) {
  #pragma unroll
  for (int m = 1; m < 64; m <<= 1) v += __shfl_xor(v, m);
  return v;
}

__device__ __forceinline__ void gload16(const void* g, void* l) {
  __builtin_amdgcn_global_load_lds(
      (const __attribute__((address_space(1))) unsigned int*)g,
      (__attribute__((address_space(3))) unsigned int*)l, 16, 0, 0);
}

// ---------------------------------------------------------------------------
// PERSISTENT 256x256 bf16 MFMA GEMM, 8-phase pipeline (R8/R9-proven),
// m-tile order staggered per block (R11, -14us).
// R13: NON-TEMPORAL epilogue stores (ext_vector type for the builtin) --
// C is never re-read; regular stores write-allocate 262KB/seam of dirty L2
// lines, evicting the A/B panels re-read from L2 each m-tile.  NT streams
// past L2.
// ---------------------------------------------------------------------------
__global__ __launch_bounds__(512, 2) void gemmP(
    const u16* __restrict__ A, const u16* __restrict__ B,
    const float* __restrict__ bias,
    float* __restrict__ C, int M, int N, int K, int MT)
{
  __shared__ u16 lds[65536];   // A: [0,32768) ; B: [32768,65536)  (u16 units)
  const int t = threadIdx.x, w = t >> 6, lane = t & 63;
  const int wm = w >> 2, wn = w & 3;
  const int r16 = lane & 15, ks = lane >> 4;

  const int bn = blockIdx.y * 256;
  const int mg = blockIdx.x;
  const int NT = K >> 6;
  const int stag = blockIdx.y & (MT - 1);     // burst de-synchronization

  auto stageH = [&](const u16* __restrict__ G, int grow0, int kt, int half, int opBase) {
    const int k0 = kt << 6;
    u16* dst = lds + opBase + ((kt & 1) << 14) + (half << 13);
    #pragma unroll
    for (int j = 0; j < 2; ++j) {
      const int r = half * 128 + j * 64 + w * 8 + (lane >> 3);
      const int s = (lane & 7) ^ (r & 7);
      gload16(G + (size_t)(grow0 + r) * K + k0 + s * 8,
              dst + j * 4096 + w * 512);
    }
  };

  for (int mt0 = 0; mt0 < MT; ++mt0) {
    const int mt = (mt0 + stag) & (MT - 1);
    const int bm = (mg * MT + mt) * 256;

    f32x4 acc[8][4];
    #pragma unroll
    for (int m = 0; m < 8; ++m)
      #pragma unroll
      for (int n = 0; n < 4; ++n) {
        f32x4 z = {0.f, 0.f, 0.f, 0.f};
        acc[m][n] = z;
      }

    __builtin_amdgcn_sched_barrier(0);
    stageH(A, bm, 0, 0, 0);
    stageH(A, bm, 0, 1, 0);
    stageH(B, bn, 0, 0, 32768);
    stageH(B, bn, 0, 1, 32768);
    __builtin_amdgcn_sched_barrier(0);
    stageH(B, bn, 1, 0, 32768);
    stageH(B, bn, 1, 1, 32768);
    asm volatile("s_waitcnt vmcnt(4)" ::: "memory");
    __builtin_amdgcn_sched_barrier(0);
    __builtin_amdgcn_s_barrier();

    for (int kt = 0; kt < NT; ++kt) {
      const u16* Ab = lds + ((kt & 1) << 14);
      const u16* Bb = lds + 32768 + ((kt & 1) << 14);
      bf16x8 bfr[4][2];

      #pragma unroll
      for (int p = 0; p < 4; ++p) {
        bf16x8 af2[2][2];
        #pragma unroll
        for (int i = 0; i < 2; ++i) {
          const int row = wm * 128 + (2 * p + i) * 16 + r16;
          af2[i][0] = *(const bf16x8*)(Ab + row * 64 + ((ks ^ (row & 7)) << 3));
          af2[i][1] = *(const bf16x8*)(Ab + row * 64 + (((4 + ks) ^ (row & 7)) << 3));
        }
        if (p == 0) {
          #pragma unroll
          for (int n = 0; n < 4; ++n) {
            const int row = wn * 64 + n * 16 + r16;
            bfr[n][0] = *(const bf16x8*)(Bb + row * 64 + ((ks ^ (row & 7)) << 3));
            bfr[n][1] = *(const bf16x8*)(Bb + row * 64 + (((4 + ks) ^ (row & 7)) << 3));
          }
        }
        if (p == 0 && kt + 1 < NT) stageH(A, bm, kt + 1, 0, 0);
        if (p == 1 && kt + 1 < NT) stageH(A, bm, kt + 1, 1, 0);
        if (p == 2 && kt + 2 < NT) stageH(B, bn, kt + 2, 0, 32768);
        if (p == 3) {
          if (kt + 2 < NT) {
            stageH(B, bn, kt + 2, 1, 32768);
            asm volatile("s_waitcnt vmcnt(4)" ::: "memory");
          } else {
            asm volatile("s_waitcnt vmcnt(0)" ::: "memory");
          }
          __builtin_amdgcn_sched_barrier(0);
        }
        __builtin_amdgcn_s_barrier();
        asm volatile("s_waitcnt lgkmcnt(0)" ::: "memory");
        __builtin_amdgcn_sched_barrier(0);
        __builtin_amdgcn_s_setprio(1);
        #pragma unroll
        for (int i = 0; i < 2; ++i)
          #pragma unroll
          for (int n = 0; n < 4; ++n) {
            acc[2 * p + i][n] = __builtin_amdgcn_mfma_f32_16x16x32_bf16(
                bfr[n][0], af2[i][0], acc[2 * p + i][n], 0, 0, 0);
            acc[2 * p + i][n] = __builtin_amdgcn_mfma_f32_16x16x32_bf16(
                bfr[n][1], af2[i][1], acc[2 * p + i][n], 0, 0, 0);
          }
        __builtin_amdgcn_s_setprio(0);
        __builtin_amdgcn_s_barrier();
      }
    }

    #pragma unroll
    for (int m = 0; m < 8; ++m) {
      const int grow = bm + wm * 128 + m * 16 + r16;
      float* Crow = C + (size_t)grow * N;
      #pragma unroll
      for (int n = 0; n < 4; ++n) {
        const int gcol = bn + wn * 64 + n * 16 + ks * 4;
        const float4 bv = *(const float4*)(bias + gcol);
        f32x4 o;
        o[0] = acc[m][n][0] + bv.x;
        o[1] = acc[m][n][1] + bv.y;
        o[2] = acc[m][n][2] + bv.z;
        o[3] = acc[m][n][3] + bv.w;
        __builtin_nontemporal_store(o, (f32x4*)(Crow + gcol));
      }
    }
  }
}

// ---------------------------------------------------------------------------
// Small GEMM, 64x128 tile, BK=32, 256 thr (4 waves, 1m x 4n, wave-tile
// 64x32), swapped-operand float4 epilogue.  C = A@B^T + bscale*bias[lvl].
// GATHER: A rows = bf16(Afp[tok[row]]), K must be 512.
// M%64==0, N%128==0, K%32==0.  Full-GPU grids for the chain/policy GEMMs.
// ---------------------------------------------------------------------------
template <bool GATHER>
__global__ __launch_bounds__(256) void gemm64(
    const float* __restrict__ Afp, const int* __restrict__ tok,
    const u16* __restrict__ A, const u16* __restrict__ B,
    const float* __restrict__ bias, int blvl, float bscale,
    float* __restrict__ C, u16* __restrict__ Cb,
    int M, int N, int K)
{
  __shared__ u16 ldsA[64 * 32];    // 4 KB
  __shared__ u16 ldsB[128 * 32];   // 8 KB
  const int t = threadIdx.x, w = t >> 6, lane = t & 63;
  const int r16 = lane & 15, ks = lane >> 4;

  const int nb = gridDim.x * gridDim.y;
  const int lid = blockIdx.y * gridDim.x + blockIdx.x;
  const int chunk = nb >> 3;
  const int nlid = (lid & 7) * chunk + (lid >> 3);
  const int bm = (nlid % gridDim.x) * 64;
  const int bn = (nlid / gridDim.x) * 128;

  const int srow = t >> 2, sslot = t & 3;

  f32x4 acc[4][2];
  #pragma unroll
  for (int m = 0; m < 4; ++m)
    #pragma unroll
    for (int n = 0; n < 2; ++n) {
      f32x4 z = {0.f, 0.f, 0.f, 0.f};
      acc[m][n] = z;
    }

  for (int k0 = 0; k0 < K; k0 += 32) {
    if (k0) __syncthreads();
    {
      const int row = srow;                       // 0..63
      const int sl = sslot ^ ((row >> 1) & 3);
      if constexpr (GATHER) {
        const float* src = Afp + (size_t)tok[bm + row] * 512 + k0 + sl * 8;
        const float4 a0 = *(const float4*)src;
        const float4 a1 = *(const float4*)(src + 4);
        bf16x8 v;
        v[0] = (short)f2b(a0.x); v[1] = (short)f2b(a0.y);
        v[2] = (short)f2b(a0.z); v[3] = (short)f2b(a0.w);
        v[4] = (short)f2b(a1.x); v[5] = (short)f2b(a1.y);
        v[6] = (short)f2b(a1.z); v[7] = (short)f2b(a1.w);
        *(bf16x8*)(ldsA + t * 8) = v;
      } else {
        gload16(A + (size_t)(bm + row) * K + k0 + sl * 8, ldsA + w * 512);
      }
    }
    #pragma unroll
    for (int i = 0; i < 2; ++i) {
      const int row = i * 64 + srow;
      const int sl = sslot ^ ((row >> 1) & 3);
      gload16(B + (size_t)(bn + row) * K + k0 + sl * 8,
              ldsB + i * 2048 + w * 512);
    }
    __syncthreads();

    bf16x8 af[4], bfr[2];
    #pragma unroll
    for (int m = 0; m < 4; ++m) {
      const int row = m * 16 + r16;
      af[m] = *(const bf16x8*)(ldsA + row * 32 + ((ks ^ ((row >> 1) & 3)) << 3));
    }
    #pragma unroll
    for (int n = 0; n < 2; ++n) {
      const int row = w * 32 + n * 16 + r16;
      bfr[n] = *(const bf16x8*)(ldsB + row * 32 + ((ks ^ ((row >> 1) & 3)) << 3));
    }
    #pragma unroll
    for (int m = 0; m < 4; ++m)
      #pragma unroll
      for (int n = 0; n < 2; ++n)
        acc[m][n] = __builtin_amdgcn_mfma_f32_16x16x32_bf16(bfr[n], af[m], acc[m][n], 0, 0, 0);
  }

  // swapped layout: row = bm+m*16+r16, cols = bn+w*32+n*16+ks*4..+3
  const float* be = bias + (size_t)(bm >> 12) * blvl;
  #pragma unroll
  for (int m = 0; m < 4; ++m) {
    const int grow = bm + m * 16 + r16;
    #pragma unroll
    for (int n = 0; n < 2; ++n) {
      const int gcol = bn + w * 32 + n * 16 + ks * 4;
      const float4 bv = *(const float4*)(be + gcol);
      float4 o;
      o.x = acc[m][n][0] + bv.x * bscale;
      o.y = acc[m][n][1] + bv.y * bscale;
      o.z = acc[m][n][2] + bv.z * bscale;
      o.w = acc[m][n][3] + bv.w * bscale;
      const size_t idx = (size_t)grow * N + gcol;
      *(float4*)(C + idx) = o;
      if (Cb) {
        ushort4 ob = { f2b(o.x), f2b(o.y), f2b(o.z), f2b(o.w) };
        *(ushort4*)(Cb + idx) = ob;
      }
    }
  }
}

// ---------------------------------------------------------------------------
// bf16 MFMA GEMM, 128x128 tile, BK=32, swapped-operand epilogue (S3+POOL).
// POOL: epilogue computes pooled = bf16((h0 + a0*S1 + a1*S2 + a2*v)*inv) -> P.
// ---------------------------------------------------------------------------
__global__ __launch_bounds__(256) void gemm_pool(
    const u16* __restrict__ A, const u16* __restrict__ B,
    const float* __restrict__ bias, float bscale,
    const float* __restrict__ h0f, const float* __restrict__ S1f,
    const float* __restrict__ S2f, const float* __restrict__ psum,
    u16* __restrict__ P,
    int M, int N, int K)
{
  __shared__ u16 ldsA[128 * 32];
  __shared__ u16 ldsB[128 * 32];
  const int t = threadIdx.x;
  const int w = t >> 6;
  const int lane = t & 63;
  const int wr = w >> 1, wc = w & 1;

  const int nb = gridDim.x * gridDim.y;
  const int lid = blockIdx.y * gridDim.x + blockIdx.x;
  const int chunk = nb >> 3;
  const int nlid = (lid & 7) * chunk + (lid >> 3);
  const int bx = nlid % gridDim.x, by = nlid / gridDim.x;

  const int bm = bx * 128, bn = by * 128;
  const int r16 = lane & 15, ks = lane >> 4;
  const int srow = t >> 2, sslot = t & 3;

  f32x4 acc[4][4];
  #pragma unroll
  for (int m = 0; m < 4; ++m)
    #pragma unroll
    for (int n = 0; n < 4; ++n) {
      f32x4 z = {0.f, 0.f, 0.f, 0.f};
      acc[m][n] = z;
    }

  for (int k0 = 0; k0 < K; k0 += 32) {
    if (k0) __syncthreads();
    #pragma unroll
    for (int i = 0; i < 2; ++i) {
      const int row = srow + i * 64;
      const int sl = sslot ^ ((row >> 1) & 3);
      gload16(A + (size_t)(bm + row) * K + k0 + sl * 8,
              ldsA + (i * 2048 + w * 512));
      gload16(B + (size_t)(bn + row) * K + k0 + sl * 8,
              ldsB + (i * 2048 + w * 512));
    }
    __syncthreads();

    bf16x8 af[4], bfr[4];
    #pragma unroll
    for (int m = 0; m < 4; ++m) {
      const int row = wr * 64 + m * 16 + r16;
      af[m] = *(const bf16x8*)(ldsA + row * 32 + ((ks ^ ((row >> 1) & 3)) << 3));
    }
    #pragma unroll
    for (int n = 0; n < 4; ++n) {
      const int row = wc * 64 + n * 16 + r16;
      bfr[n] = *(const bf16x8*)(ldsB + row * 32 + ((ks ^ ((row >> 1) & 3)) << 3));
    }
    #pragma unroll
    for (int m = 0; m < 4; ++m)
      #pragma unroll
      for (int n = 0; n < 4; ++n)
        acc[m][n] = __builtin_amdgcn_mfma_f32_16x16x32_bf16(bfr[n], af[m], acc[m][n], 0, 0, 0);
  }

  const float a0 = (psum[0] * (1.f / 4096.f) >= 0.5f) ? 1.f : 0.f;
  const float a1 = a0 * ((psum[1] * (1.f / 4096.f) >= 0.5f) ? 1.f : 0.f);
  const float a2 = a1 * ((psum[2] * (1.f / 4096.f) >= 0.5f) ? 1.f : 0.f);
  const float cnt = 1.f + a0 * 2.f + a1 * 4.f + a2 * 8.f;
  const float inv = 1.f / fmaxf(cnt, 1e-8f);

  #pragma unroll
  for (int m = 0; m < 4; ++m) {
    const int grow = bm + wr * 64 + m * 16 + r16;
    #pragma unroll
    for (int n = 0; n < 4; ++n) {
      const int gcol = bn + wc * 64 + n * 16 + ks * 4;
      const float4 bv = *(const float4*)(bias + gcol);
      float4 o;
      o.x = acc[m][n][0] + bv.x * bscale;
      o.y = acc[m][n][1] + bv.y * bscale;
      o.z = acc[m][n][2] + bv.z * bscale;
      o.w = acc[m][n][3] + bv.w * bscale;
      const size_t idx = (size_t)grow * N + gcol;
      const float4 h = *(const float4*)(h0f + idx);
      const float4 s1 = *(const float4*)(S1f + idx);
      const float4 s2 = *(const float4*)(S2f + idx);
      ushort4 ob;
      ob.x = f2b((h.x + a0 * s1.x + a1 * s2.x + a2 * o.x) * inv);
      ob.y = f2b((h.y + a0 * s1.y + a1 * s2.y + a2 * o.y) * inv);
      ob.z = f2b((h.z + a0 * s1.z + a1 * s2.z + a2 * o.z) * inv);
      ob.w = f2b((h.w + a0 * s1.w + a1 * s2.w + a2 * o.w) * inv);
      *(ushort4*)(P + idx) = ob;
    }
  }
}

// ---------------------------------------------------------------------------
// fused weight prep + out_w conversion, role-dispatched (grid 16676)
// ---------------------------------------------------------------------------
__global__ __launch_bounds__(256) void prep_misc(
    const float* __restrict__ cf_w, const float* __restrict__ cf_b,
    const float* __restrict__ sib, const float* __restrict__ proj_w,
    const float* __restrict__ f1w, const float* __restrict__ f1b,
    const float* __restrict__ f2w, const float* __restrict__ pde,
    const float* __restrict__ out_w,
    u16* __restrict__ wsum_b, u16* __restrict__ projw_b,
    u16* __restrict__ f1w512b, u16* __restrict__ f2wb,
    float* __restrict__ cvec, float* __restrict__ psum,
    float* __restrict__ y1bias, u16* __restrict__ outw_b)
{
  const int b = blockIdx.x, t = threadIdx.x;
  if (b >= 676) {
    const int idx = (b - 676) * 256 + t;
    const float4 v = ((const float4*)out_w)[idx];
    ushort4 o = { f2b(v.x), f2b(v.y), f2b(v.z), f2b(v.w) };
    ((ushort4*)outw_b)[idx] = o;
  } else if (b < 256) {
    const int idx = b * 256 + t;
    const float4 a = ((const float4*)cf_w)[idx];
    const float4 c = ((const float4*)(cf_w + 262144))[idx];
    ushort4 o = { f2b(a.x + c.x), f2b(a.y + c.y), f2b(a.z + c.z), f2b(a.w + c.w) };
    ((ushort4*)wsum_b)[idx] = o;
  } else if (b < 512) {
    const int idx = (b - 256) * 256 + t;
    const float4 v = ((const float4*)proj_w)[idx];
    ushort4 o = { f2b(v.x), f2b(v.y), f2b(v.z), f2b(v.w) };
    ((ushort4*)projw_b)[idx] = o;
  } else if (b < 640) {
    const int fi = (b - 512) * 256 + t;
    const int row = fi >> 7, c4 = fi & 127;
    const float4 v = *(const float4*)(f1w + (size_t)row * 640 + c4 * 4);
    ushort4 o = { f2b(v.x), f2b(v.y), f2b(v.z), f2b(v.w) };
    ((ushort4*)f1w512b)[row * 128 + c4] = o;
  } else if (b < 672) {
    const int idx = (b - 640) * 256 + t;
    const float4 v = ((const float4*)f2w)[idx];
    ushort4 o = { f2b(v.x), f2b(v.y), f2b(v.z), f2b(v.w) };
    ((ushort4*)f2wb)[idx] = o;
  } else if (b < 675) {
    const int l = b - 672, j = t;
    const float* wrow = f1w + (size_t)j * 640 + 512;
    const float* p = pde + l * 128;
    float s = f1b[j];
    #pragma unroll 4
    for (int k = 0; k < 128; ++k) s += wrow[k] * p[k];
    y1bias[l * 256 + j] = s;
  } else {
    cvec[t]       = cf_b[t]       + cf_b[512 + t] + SIB_SCALE_F * (sib[t]       + sib[512 + t]);
    cvec[256 + t] = cf_b[256 + t] + cf_b[768 + t] + SIB_SCALE_F * (sib[256 + t] + sib[768 + t]);
    if (t < 3) psum[t] = 0.f;
  }
}

// ---------------------------------------------------------------------------
// batched policy input over 3 levels: X[g] = bf16(LN(S_l/2^l + 0.01*dep_l))
// ---------------------------------------------------------------------------
__global__ __launch_bounds__(256) void mean_ln_concat_b(
    const float* __restrict__ S0, const float* __restrict__ S1,
    const float* __restrict__ S2,
    const float* __restrict__ dep,
    const float* __restrict__ g, const float* __restrict__ b,
    u16* __restrict__ X)
{
  const int wid = threadIdx.x >> 6, lane = threadIdx.x & 63;
  const int gr = blockIdx.x * 4 + wid;          // 0..12287
  const int l = gr >> 12, n = gr & 4095;
  const float* Sr = (l == 0 ? S0 : l == 1 ? S1 : S2) + (size_t)n * 512;
  const float invM = (l == 0 ? 1.f : l == 1 ? 0.5f : 0.25f);
  const float* depl = dep + 512 * l;
  const int c0 = lane * 8;
  float x[8];
  float s = 0.f, sq = 0.f;
  #pragma unroll
  for (int i = 0; i < 8; ++i) {
    const float v = Sr[c0 + i] * invM + 0.01f * depl[c0 + i];
    x[i] = v; s += v; sq += v * v;
  }
  s = wred(s); sq = wred(sq);
  const float mean = s * (1.f / 512.f);
  const float var = sq * (1.f / 512.f) - mean * mean;
  const float rs = rsqrtf(var + 1e-5f);
  ushort4 o0, o1;
  o0.x = f2b((x[0] - mean) * rs * g[c0 + 0] + b[c0 + 0]);
  o0.y = f2b((x[1] - mean) * rs * g[c0 + 1] + b[c0 + 1]);
  o0.z = f2b((x[2] - mean) * rs * g[c0 + 2] + b[c0 + 2]);
  o0.w = f2b((x[3] - mean) * rs * g[c0 + 3] + b[c0 + 3]);
  o1.x = f2b((x[4] - mean) * rs * g[c0 + 4] + b[c0 + 4]);
  o1.y = f2b((x[5] - mean) * rs * g[c0 + 5] + b[c0 + 5]);
  o1.z = f2b((x[6] - mean) * rs * g[c0 + 6] + b[c0 + 6]);
  o1.w = f2b((x[7] - mean) * rs * g[c0 + 7] + b[c0 + 7]);
  ushort4* Xr = (ushort4*)(X + (size_t)gr * 512);
  Xr[lane * 2]     = o0;
  Xr[lane * 2 + 1] = o1;
}

// LN + relu over 256 cols, fp32 in -> bf16 out
__global__ __launch_bounds__(256) void ln_relu_b256(
    const float* __restrict__ X, const float* __restrict__ g,
    const float* __restrict__ b, u16* __restrict__ O)
{
  const int wid = threadIdx.x >> 6, lane = threadIdx.x & 63;
  const int n = blockIdx.x * 4 + wid;
  const float* Xr = X + (size_t)n * 256;
  float x[4];
  float s = 0.f, sq = 0.f;
  #pragma unroll
  for (int i = 0; i < 4; ++i) {
    x[i] = Xr[lane * 4 + i]; s += x[i]; sq += x[i] * x[i];
  }
  s = wred(s); sq = wred(sq);
  const float mean = s * (1.f / 256.f);
  const float var = sq * (1.f / 256.f) - mean * mean;
  const float rs = rsqrtf(var + 1e-5f);
  ushort4 o;
  o.x = f2b(fmaxf((x[0] - mean) * rs * g[lane * 4 + 0] + b[lane * 4 + 0], 0.f));
  o.y = f2b(fmaxf((x[1] - mean) * rs * g[lane * 4 + 1] + b[lane * 4 + 1], 0.f));
  o.z = f2b(fmaxf((x[2] - mean) * rs * g[lane * 4 + 2] + b[lane * 4 + 2], 0.f));
  o.w = f2b(fmaxf((x[3] - mean) * rs * g[lane * 4 + 3] + b[lane * 4 + 3], 0.f));
  ((ushort4*)(O + (size_t)n * 256))[lane] = o;
}

// fused: LN(128) + relu + dot(pow_w) + sigmoid + clip + per-level atomicAdd
__global__ __launch_bounds__(256) void ln_policy128(
    const float* __restrict__ Y2, const float* __restrict__ g,
    const float* __restrict__ b, const float* __restrict__ pw,
    const float* __restrict__ pb, float* __restrict__ psum)
{
  __shared__ float part[4];
  const int wid = threadIdx.x >> 6, lane = threadIdx.x & 63;
  const int gr = blockIdx.x * 4 + wid;
  const float* Xr = Y2 + (size_t)gr * 128;
  float x[2];
  float s = 0.f, sq = 0.f;
  #pragma unroll
  for (int i = 0; i < 2; ++i) {
    x[i] = Xr[lane * 2 + i]; s += x[i]; sq += x[i] * x[i];
  }
  s = wred(s); sq = wred(sq);
  const float mean = s * (1.f / 128.f);
  const float var = sq * (1.f / 128.f) - mean * mean;
  const float rs = rsqrtf(var + 1e-5f);
  float z = 0.f;
  #pragma unroll
  for (int i = 0; i < 2; ++i) {
    const int c = lane * 2 + i;
    const float v = fmaxf((x[i] - mean) * rs * g[c] + b[c], 0.f);
    z += v * pw[c];
  }
  z = wred(z);
  if (lane == 0) {
    const float p = 1.f / (1.f + expf(-(z + pb[0])));
    part[wid] = fminf(fmaxf(p, 1e-7f), 1.f - 1e-7f);
  }
  __syncthreads();
  if (threadIdx.x == 0)
    atomicAdd(psum + (gr >> 12), part[0] + part[1] + part[2] + part[3]);
}

// ---------------------------------------------------------------------------
extern "C" void kernel_launch(void* const* d_in, const int* in_sizes, int n_in,
                              void* d_out, int out_size, void* d_ws, size_t ws_size,
                              hipStream_t stream) {
  const int*   tok    = (const int*)  d_in[0];
  const float* emb    = (const float*)d_in[1];
  const float* proj_w = (const float*)d_in[2];
  const float* proj_b = (const float*)d_in[3];
  const float* cf_w   = (const float*)d_in[4];
  const float* cf_b   = (const float*)d_in[5];
  const float* in_g   = (const float*)d_in[6];
  const float* in_b   = (const float*)d_in[7];
  const float* pde    = (const float*)d_in[8];
  const float* f1w    = (const float*)d_in[9];
  const float* f1b    = (const float*)d_in[10];
  const float* n1g    = (const float*)d_in[11];
  const float* n1b    = (const float*)d_in[12];
  const float* f2w    = (const float*)d_in[13];
  const float* f2bias = (const float*)d_in[14];
  const float* n2g    = (const float*)d_in[15];
  const float* n2b    = (const float*)d_in[16];
  const float* pow_w  = (const float*)d_in[17];
  const float* pow_b  = (const float*)d_in[18];
  const float* sib    = (const float*)d_in[19];
  const float* dep    = (const float*)d_in[20];
  const float* out_w  = (const float*)d_in[21];
  const float* out_b  = (const float*)d_in[22];
  float* out = (float*)d_out;

  char* ws = (char*)d_ws;
  size_t off = 0;
  auto alloc = [&](size_t bytes) -> void* {
    void* p = ws + off;
    off += (bytes + 255) & ~(size_t)255;
    return p;
  };
  u16*   outw_b  = (u16*)  alloc((size_t)32000 * 512 * 2);
  u16*   projw_b = (u16*)  alloc((size_t)512 * 512 * 2);
  u16*   wsum_b  = (u16*)  alloc((size_t)512 * 512 * 2);
  u16*   f1w512b = (u16*)  alloc((size_t)256 * 512 * 2);
  u16*   f2wb    = (u16*)  alloc((size_t)128 * 256 * 2);
  float* h0f     = (float*)alloc((size_t)4096 * 512 * 4);
  u16*   h0b     = (u16*)  alloc((size_t)4096 * 512 * 2);
  float* S1f     = (float*)alloc((size_t)4096 * 512 * 4);
  u16*   S1b     = (u16*)  alloc((size_t)4096 * 512 * 2);
  float* S2f     = (float*)alloc((size_t)4096 * 512 * 4);
  u16*   S2b     = (u16*)  alloc((size_t)4096 * 512 * 2);
  u16*   X       = (u16*)  alloc((size_t)12288 * 512 * 2);
  float* Y1      = (float*)alloc((size_t)12288 * 256 * 4);
  u16*   Y1b     = (u16*)  alloc((size_t)12288 * 256 * 2);
  float* Y2      = (float*)alloc((size_t)12288 * 128 * 4);
  float* y1bias  = (float*)alloc(3 * 256 * 4);
  float* cvec    = (float*)alloc(512 * 4);
  float* psum    = (float*)alloc(256);
  u16*   poolb   = (u16*)  alloc((size_t)4096 * 512 * 2);

  prep_misc<<<16676, 256, 0, stream>>>(cf_w, cf_b, sib, proj_w, f1w, f1b, f2w,
                                       pde, out_w,
                                       wsum_b, projw_b, f1w512b, f2wb,
                                       cvec, psum, y1bias, outw_b);

  // h0 = emb[tok] @ proj_w^T + proj_b   (64x128 tile, grid 256 = full GPU)
  gemm64<true><<<dim3(64, 4), 256, 0, stream>>>(
      emb, tok, nullptr, projw_b, proj_b, 0, 1.f, h0f, h0b, 4096, 512, 512);
  // S1, S2
  gemm64<false><<<dim3(64, 4), 256, 0, stream>>>(
      nullptr, nullptr, h0b, wsum_b, cvec, 0, 1.f, S1f, S1b, 4096, 512, 512);
  gemm64<false><<<dim3(64, 4), 256, 0, stream>>>(
      nullptr, nullptr, S1b, wsum_b, cvec, 0, 2.f, S2f, S2b, 4096, 512, 512);

  // policy, 3 levels batched
  mean_ln_concat_b<<<3072, 256, 0, stream>>>(h0f, S1f, S2f, dep, in_g, in_b, X);
  gemm64<false><<<dim3(192, 2), 256, 0, stream>>>(
      nullptr, nullptr, X, f1w512b, y1bias, 256, 1.f, Y1, nullptr, 12288, 256, 512);
  ln_relu_b256<<<3072, 256, 0, stream>>>(Y1, n1g, n1b, Y1b);
  gemm64<false><<<dim3(192, 1), 256, 0, stream>>>(
      nullptr, nullptr, Y1b, f2wb, f2bias, 0, 1.f, Y2, nullptr, 12288, 128, 256);
  ln_policy128<<<3072, 256, 0, stream>>>(Y2, n2g, n2b, pow_w, pow_b, psum);

  // S3 GEMM fused with pooling (128^2, proven)
  gemm_pool<<<dim3(32, 4), 256, 0, stream>>>(
      S2b, wsum_b, cvec, 4.f, h0f, S1f, S2f, psum, poolb, 4096, 512, 512);

  // out = pooled @ out_w^T + out_b (4096 x 32000 x 512)
  // persistent 256x256 8-phase, staggered m-tiles, NT stores
  gemmP<<<dim3(2, 125), 512, 0, stream>>>(poolb, outw_b, out_b,
                                          out, 4096, 32000, 512, 8);
}